// Round 2
// baseline (232.946 us; speedup 1.0000x reference)
//
#include <hip/hip_runtime.h>
#include <math.h>

// Batched expm of 4x4 fp32 matrices: out[m] = expm(A[m] * t[m / S]).
// One thread per matrix, all state in registers as packed float2 pairs
// (targets v_pk_fma_f32 — gfx950's 2x fp32 rate).
//
// Scaling-and-squaring, same structure as reference:
//   s = clip(ceil(log2(max(||Qt||_inf,1e-30)/0.5)), 0, 16)
//   Xs = Qt * 2^-s ; P = Taylor_8(Xs) ; P = P^(2^s)
// Degree-8 Taylor (tail 0.5^9/9! ~ 5e-9, below fp32 eps) via
// Paterson-Stockmeyer: P = B0 + X3*(B1 + X3*B2), Bj = aj*I + bj*X + cj*X2
// -> 4 matmuls total instead of 9 (R0) / 16 (reference).

typedef float v2f __attribute__((ext_vector_type(2)));

// C += A * B for 4x4 stored as [row][pair] of float2 (pair 0 = cols 0..1).
__device__ __forceinline__ void mm4(const v2f (&Am)[4][2],
                                    const v2f (&Bm)[4][2],
                                    v2f (&Cm)[4][2])
{
#pragma unroll
    for (int i = 0; i < 4; ++i) {
        const float a0 = Am[i][0][0], a1 = Am[i][0][1];
        const float a2 = Am[i][1][0], a3 = Am[i][1][1];
#pragma unroll
        for (int p = 0; p < 2; ++p) {
            v2f acc = Cm[i][p];
            acc += a0 * Bm[0][p];   // packed fma: both cols of the pair
            acc += a1 * Bm[1][p];
            acc += a2 * Bm[2][p];
            acc += a3 * Bm[3][p];
            Cm[i][p] = acc;
        }
    }
}

__global__ void __launch_bounds__(256) expm4_kernel(
    const float* __restrict__ A,
    const float* __restrict__ tvec,
    float* __restrict__ out,
    int M, int S)
{
    const int m = blockIdx.x * 256 + threadIdx.x;
    if (m >= M) return;

    const float t = tvec[m / S];   // wave-uniform in practice

    // ---- load A[m] (64 B contiguous) ----
    const float4* Ap = reinterpret_cast<const float4*>(A) + (size_t)m * 4;
    float4 r[4];
#pragma unroll
    for (int i = 0; i < 4; ++i) r[i] = Ap[i];

    // ---- inf-norm on raw A; ||A*t|| = t*||A|| (t >= 0) ----
    float nrm = 0.0f;
#pragma unroll
    for (int i = 0; i < 4; ++i) {
        float rs = fabsf(r[i].x) + fabsf(r[i].y) + fabsf(r[i].z) + fabsf(r[i].w);
        nrm = fmaxf(nrm, rs);
    }
    float sf = ceilf(log2f(fmaxf(t * nrm, 1e-30f) * 2.0f));  // log2(nrm/0.5)
    sf = fminf(fmaxf(sf, 0.0f), 16.0f);
    const int   si = (int)sf;
    const float c  = t * ldexpf(1.0f, -si);   // fused t * 2^-s

    // ---- X = A * c, packed layout ----
    v2f X[4][2];
#pragma unroll
    for (int i = 0; i < 4; ++i) {
        X[i][0][0] = r[i].x * c;  X[i][0][1] = r[i].y * c;
        X[i][1][0] = r[i].z * c;  X[i][1][1] = r[i].w * c;
    }

    // ---- powers ----
    v2f X2[4][2] = {};  mm4(X,  X, X2);   // X^2
    v2f X3[4][2] = {};  mm4(X2, X, X3);   // X^3

    constexpr float c2 = 1.f/2.f,   c3 = 1.f/6.f,    c4 = 1.f/24.f;
    constexpr float c5 = 1.f/120.f, c6 = 1.f/720.f,  c7 = 1.f/5040.f;
    constexpr float c8 = 1.f/40320.f;

    // B2 = c6*I + c7*X + c8*X2
    v2f B2[4][2];
#pragma unroll
    for (int i = 0; i < 4; ++i) {
#pragma unroll
        for (int p = 0; p < 2; ++p) B2[i][p] = c7 * X[i][p] + c8 * X2[i][p];
    }
    B2[0][0][0] += c6; B2[1][0][1] += c6; B2[2][1][0] += c6; B2[3][1][1] += c6;

    // T1 = B1 + X3*B2,  B1 = c3*I + c4*X + c5*X2
    v2f T1[4][2];
#pragma unroll
    for (int i = 0; i < 4; ++i) {
#pragma unroll
        for (int p = 0; p < 2; ++p) T1[i][p] = c4 * X[i][p] + c5 * X2[i][p];
    }
    T1[0][0][0] += c3; T1[1][0][1] += c3; T1[2][1][0] += c3; T1[3][1][1] += c3;
    mm4(X3, B2, T1);

    // P = B0 + X3*T1,  B0 = I + X + c2*X2
    v2f P[4][2];
#pragma unroll
    for (int i = 0; i < 4; ++i) {
#pragma unroll
        for (int p = 0; p < 2; ++p) P[i][p] = X[i][p] + c2 * X2[i][p];
    }
    P[0][0][0] += 1.f; P[1][0][1] += 1.f; P[2][1][0] += 1.f; P[3][1][1] += 1.f;
    mm4(X3, T1, P);

    // ---- undo scaling: square si times (per-lane trip count) ----
    for (int it = 0; it < si; ++it) {
        v2f Q[4][2] = {};
        mm4(P, P, Q);
#pragma unroll
        for (int i = 0; i < 4; ++i) {
            P[i][0] = Q[i][0];
            P[i][1] = Q[i][1];
        }
    }

    // ---- store (64 B contiguous) ----
    float4* Op = reinterpret_cast<float4*>(out) + (size_t)m * 4;
#pragma unroll
    for (int i = 0; i < 4; ++i) {
        float4 v;
        v.x = P[i][0][0]; v.y = P[i][0][1];
        v.z = P[i][1][0]; v.w = P[i][1][1];
        Op[i] = v;
    }
}

extern "C" void kernel_launch(void* const* d_in, const int* in_sizes, int n_in,
                              void* d_out, int out_size, void* d_ws, size_t ws_size,
                              hipStream_t stream) {
    const float* A    = (const float*)d_in[0];   // [B, S, 4, 4] fp32
    const float* tvec = (const float*)d_in[1];   // [B] fp32
    float* out        = (float*)d_out;           // [B, S, 4, 4] fp32

    const int B = in_sizes[1];
    const int M = in_sizes[0] / 16;              // total 4x4 matrices
    const int S = M / B;                         // matrices per batch item

    const int threads = 256;
    const int blocks  = (M + threads - 1) / threads;
    expm4_kernel<<<blocks, threads, 0, stream>>>(A, tvec, out, M, S);
}

// Round 3
// 230.448 us; speedup vs baseline: 1.0108x; 1.0108x over previous
//
#include <hip/hip_runtime.h>
#include <math.h>

// Batched expm of 4x4 fp32 matrices: out[m] = expm(A[m] * t[m / S]).
//
// R2 change: LDS-staged coalescing. One thread still computes one matrix
// (registers, packed float2 math -> v_pk_fma_f32), but global traffic goes
// through LDS so every global instruction is lane-contiguous (16 cache
// lines/instr instead of 64 with the naive 64B-per-thread pattern).
//
// LDS layout: matrix stride 9 float2s (8 data + 1 pad). Bank math: phase-2
// reads hit word addr 18*tid + 2j -> 18*tid mod 32 covers all 16 even banks
// -> 4-way conflict (~1.6x, cheap). Staging writes/reads same 4-way.
//
// Math: scaling-and-squaring, degree-8 Taylor via Paterson-Stockmeyer
// (4 matmuls), per-lane squaring count. Tail 0.5^9/9! ~ 5e-9 << fp32 eps.

typedef float v2f __attribute__((ext_vector_type(2)));

constexpr int MAT_PER_BLOCK = 256;
constexpr int LSTR = 9;  // float2 units per matrix slot in LDS (8 + 1 pad)

// C += A * B for 4x4 stored as [row][pair] of float2 (pair 0 = cols 0..1).
__device__ __forceinline__ void mm4(const v2f (&Am)[4][2],
                                    const v2f (&Bm)[4][2],
                                    v2f (&Cm)[4][2])
{
#pragma unroll
    for (int i = 0; i < 4; ++i) {
        const float a0 = Am[i][0][0], a1 = Am[i][0][1];
        const float a2 = Am[i][1][0], a3 = Am[i][1][1];
#pragma unroll
        for (int p = 0; p < 2; ++p) {
            v2f acc = Cm[i][p];
            acc += a0 * Bm[0][p];
            acc += a1 * Bm[1][p];
            acc += a2 * Bm[2][p];
            acc += a3 * Bm[3][p];
            Cm[i][p] = acc;
        }
    }
}

__global__ void __launch_bounds__(256) expm4_kernel(
    const float* __restrict__ A,
    const float* __restrict__ tvec,
    float* __restrict__ out,
    int M, int S)
{
    __shared__ v2f lds[MAT_PER_BLOCK * LSTR];   // 18 KB

    const int tid = threadIdx.x;
    const int blockBase = blockIdx.x * MAT_PER_BLOCK;   // first matrix of tile
    const int m = blockBase + tid;

    // ---- phase 1: coalesced global -> LDS ----
    const float4* Ag = reinterpret_cast<const float4*>(A) + (size_t)blockBase * 4;
#pragma unroll
    for (int k = 0; k < 4; ++k) {
        const int F = k * 256 + tid;          // float4 index within tile
        float4 v = Ag[F];                     // lanes contiguous -> coalesced
        const int mat = F >> 2, q = F & 3;
        v2f* dst = &lds[mat * LSTR + 2 * q];
        dst[0] = v2f{v.x, v.y};
        dst[1] = v2f{v.z, v.w};
    }
    __syncthreads();

    // ---- phase 2: own matrix from LDS, compute expm in registers ----
    const float t = tvec[m / S];

    v2f R[8];
#pragma unroll
    for (int j = 0; j < 8; ++j) R[j] = lds[tid * LSTR + j];

    // inf-norm on raw A; ||A*t|| = t * ||A|| (t >= 0)
    float nrm = 0.0f;
#pragma unroll
    for (int i = 0; i < 4; ++i) {
        float rs = fabsf(R[2*i][0]) + fabsf(R[2*i][1])
                 + fabsf(R[2*i+1][0]) + fabsf(R[2*i+1][1]);
        nrm = fmaxf(nrm, rs);
    }
    float sf = ceilf(log2f(fmaxf(t * nrm, 1e-30f) * 2.0f));  // log2(||Qt||/0.5)
    sf = fminf(fmaxf(sf, 0.0f), 16.0f);
    const int   si = (int)sf;
    const float c  = t * ldexpf(1.0f, -si);   // fused t * 2^-s

    v2f X[4][2];
#pragma unroll
    for (int i = 0; i < 4; ++i) {
        X[i][0] = R[2*i]   * c;
        X[i][1] = R[2*i+1] * c;
    }

    v2f X2[4][2] = {};  mm4(X,  X, X2);   // X^2
    v2f X3[4][2] = {};  mm4(X2, X, X3);   // X^3

    constexpr float c2 = 1.f/2.f,   c3 = 1.f/6.f,    c4 = 1.f/24.f;
    constexpr float c5 = 1.f/120.f, c6 = 1.f/720.f,  c7 = 1.f/5040.f;
    constexpr float c8 = 1.f/40320.f;

    // B2 = c6*I + c7*X + c8*X2
    v2f B2[4][2];
#pragma unroll
    for (int i = 0; i < 4; ++i) {
#pragma unroll
        for (int p = 0; p < 2; ++p) B2[i][p] = c7 * X[i][p] + c8 * X2[i][p];
    }
    B2[0][0][0] += c6; B2[1][0][1] += c6; B2[2][1][0] += c6; B2[3][1][1] += c6;

    // T1 = B1 + X3*B2,  B1 = c3*I + c4*X + c5*X2
    v2f T1[4][2];
#pragma unroll
    for (int i = 0; i < 4; ++i) {
#pragma unroll
        for (int p = 0; p < 2; ++p) T1[i][p] = c4 * X[i][p] + c5 * X2[i][p];
    }
    T1[0][0][0] += c3; T1[1][0][1] += c3; T1[2][1][0] += c3; T1[3][1][1] += c3;
    mm4(X3, B2, T1);

    // P = B0 + X3*T1,  B0 = I + X + c2*X2
    v2f P[4][2];
#pragma unroll
    for (int i = 0; i < 4; ++i) {
#pragma unroll
        for (int p = 0; p < 2; ++p) P[i][p] = X[i][p] + c2 * X2[i][p];
    }
    P[0][0][0] += 1.f; P[1][0][1] += 1.f; P[2][1][0] += 1.f; P[3][1][1] += 1.f;
    mm4(X3, T1, P);

    // undo scaling: square si times (per-lane trip count)
    for (int it = 0; it < si; ++it) {
        v2f Q[4][2] = {};
        mm4(P, P, Q);
#pragma unroll
        for (int i = 0; i < 4; ++i) { P[i][0] = Q[i][0]; P[i][1] = Q[i][1]; }
    }

    // write result back to OWN slot (no sync needed vs own reads)
#pragma unroll
    for (int i = 0; i < 4; ++i) {
        lds[tid * LSTR + 2*i]     = P[i][0];
        lds[tid * LSTR + 2*i + 1] = P[i][1];
    }
    __syncthreads();

    // ---- phase 3: LDS -> coalesced global ----
    float4* Og = reinterpret_cast<float4*>(out) + (size_t)blockBase * 4;
#pragma unroll
    for (int k = 0; k < 4; ++k) {
        const int F = k * 256 + tid;
        const int mat = F >> 2, q = F & 3;
        const v2f* src = &lds[mat * LSTR + 2 * q];
        v2f a = src[0], b = src[1];
        Og[F] = float4{a[0], a[1], b[0], b[1]};   // lanes contiguous
    }
}

// Guarded per-thread fallback for a partial tail tile (not launched when
// M % 256 == 0, which holds for this problem).
__global__ void __launch_bounds__(256) expm4_tail(
    const float* __restrict__ A,
    const float* __restrict__ tvec,
    float* __restrict__ out,
    int M, int S, int startM)
{
    const int m = startM + blockIdx.x * 256 + threadIdx.x;
    if (m >= M) return;
    const float t = tvec[m / S];

    const float4* Ap = reinterpret_cast<const float4*>(A) + (size_t)m * 4;
    float4 r[4];
#pragma unroll
    for (int i = 0; i < 4; ++i) r[i] = Ap[i];

    float nrm = 0.0f;
#pragma unroll
    for (int i = 0; i < 4; ++i) {
        float rs = fabsf(r[i].x) + fabsf(r[i].y) + fabsf(r[i].z) + fabsf(r[i].w);
        nrm = fmaxf(nrm, rs);
    }
    float sf = ceilf(log2f(fmaxf(t * nrm, 1e-30f) * 2.0f));
    sf = fminf(fmaxf(sf, 0.0f), 16.0f);
    const int   si = (int)sf;
    const float c  = t * ldexpf(1.0f, -si);

    v2f X[4][2];
#pragma unroll
    for (int i = 0; i < 4; ++i) {
        X[i][0] = v2f{r[i].x, r[i].y} * c;
        X[i][1] = v2f{r[i].z, r[i].w} * c;
    }
    v2f X2[4][2] = {};  mm4(X,  X, X2);
    v2f X3[4][2] = {};  mm4(X2, X, X3);

    constexpr float c2 = 1.f/2.f,   c3 = 1.f/6.f,    c4 = 1.f/24.f;
    constexpr float c5 = 1.f/120.f, c6 = 1.f/720.f,  c7 = 1.f/5040.f;
    constexpr float c8 = 1.f/40320.f;

    v2f B2[4][2];
#pragma unroll
    for (int i = 0; i < 4; ++i)
#pragma unroll
        for (int p = 0; p < 2; ++p) B2[i][p] = c7 * X[i][p] + c8 * X2[i][p];
    B2[0][0][0] += c6; B2[1][0][1] += c6; B2[2][1][0] += c6; B2[3][1][1] += c6;

    v2f T1[4][2];
#pragma unroll
    for (int i = 0; i < 4; ++i)
#pragma unroll
        for (int p = 0; p < 2; ++p) T1[i][p] = c4 * X[i][p] + c5 * X2[i][p];
    T1[0][0][0] += c3; T1[1][0][1] += c3; T1[2][1][0] += c3; T1[3][1][1] += c3;
    mm4(X3, B2, T1);

    v2f P[4][2];
#pragma unroll
    for (int i = 0; i < 4; ++i)
#pragma unroll
        for (int p = 0; p < 2; ++p) P[i][p] = X[i][p] + c2 * X2[i][p];
    P[0][0][0] += 1.f; P[1][0][1] += 1.f; P[2][1][0] += 1.f; P[3][1][1] += 1.f;
    mm4(X3, T1, P);

    for (int it = 0; it < si; ++it) {
        v2f Q[4][2] = {};
        mm4(P, P, Q);
#pragma unroll
        for (int i = 0; i < 4; ++i) { P[i][0] = Q[i][0]; P[i][1] = Q[i][1]; }
    }

    float4* Op = reinterpret_cast<float4*>(out) + (size_t)m * 4;
#pragma unroll
    for (int i = 0; i < 4; ++i)
        Op[i] = float4{P[i][0][0], P[i][0][1], P[i][1][0], P[i][1][1]};
}

extern "C" void kernel_launch(void* const* d_in, const int* in_sizes, int n_in,
                              void* d_out, int out_size, void* d_ws, size_t ws_size,
                              hipStream_t stream) {
    const float* A    = (const float*)d_in[0];   // [B, S, 4, 4] fp32
    const float* tvec = (const float*)d_in[1];   // [B] fp32
    float* out        = (float*)d_out;           // [B, S, 4, 4] fp32

    const int B = in_sizes[1];
    const int M = in_sizes[0] / 16;              // total 4x4 matrices
    const int S = M / B;                         // matrices per batch item

    const int fullBlocks = M / MAT_PER_BLOCK;
    if (fullBlocks > 0)
        expm4_kernel<<<fullBlocks, 256, 0, stream>>>(A, tvec, out, M, S);

    const int rem = M - fullBlocks * MAT_PER_BLOCK;
    if (rem > 0) {
        expm4_tail<<<(rem + 255) / 256, 256, 0, stream>>>(
            A, tvec, out, M, S, fullBlocks * MAT_PER_BLOCK);
    }
}